// Round 1
// baseline (3565.319 us; speedup 1.0000x reference)
//
#include <hip/hip_runtime.h>

#define TPB 256

__device__ __forceinline__ void atomic_add_f32(float* p, float v) {
#if defined(__gfx90a__) || defined(__gfx940__) || defined(__gfx941__) || defined(__gfx942__) || defined(__gfx950__)
    unsafeAtomicAdd(p, v);
#else
    atomicAdd(p, v);
#endif
}

// ---- degree / norm ----------------------------------------------------------
__global__ void k_deg_init(float* __restrict__ deg, int n) {
    int i = blockIdx.x * blockDim.x + threadIdx.x;
    if (i < n) deg[i] = 1.0f;   // self-loop
}

__global__ void k_deg_count(const int* __restrict__ dst, float* __restrict__ deg, int E) {
    int e = blockIdx.x * blockDim.x + threadIdx.x;
    if (e < E) atomic_add_f32(&deg[dst[e]], 1.0f);
}

__global__ void k_rsqrt(float* __restrict__ deg, int n) {
    int i = blockIdx.x * blockDim.x + threadIdx.x;
    if (i < n) deg[i] = rsqrtf(deg[i]);   // deg >= 1 always (self-loop)
}

// ---- layer 1: g1 = dinv * (x @ W1), acc1 init = g1 (self-loop term) ---------
__global__ void k_gemm1(const float* __restrict__ x, const float* __restrict__ W1,
                        const float* __restrict__ dinv,
                        float* __restrict__ g1, float* __restrict__ acc1, int n) {
    __shared__ float Ws[16 * 48];
    for (int i = threadIdx.x; i < 16 * 48; i += blockDim.x) Ws[i] = W1[i];
    __syncthreads();
    int t = blockIdx.x * blockDim.x + threadIdx.x;
    int v = t / 48, c = t % 48;
    if (v >= n) return;
    const float* xr = x + v * 16;
    float s = 0.f;
#pragma unroll
    for (int k = 0; k < 16; ++k) s = fmaf(xr[k], Ws[k * 48 + c], s);
    s *= dinv[v];
    g1[t] = s;
    acc1[t] = s;
}

// ---- scatter layer 1: acc1[dst] += g1[src], 12 float4-quads per edge --------
__global__ void k_scatter1(const int* __restrict__ src, const int* __restrict__ dst,
                           const float* __restrict__ g1, float* __restrict__ acc1, int E) {
    long long t = (long long)blockIdx.x * blockDim.x + threadIdx.x;
    int e = (int)(t / 12), q = (int)(t % 12);
    if (e >= E) return;
    int s = src[e], d = dst[e];
    float4 val = *reinterpret_cast<const float4*>(g1 + (long long)s * 48 + q * 4);
    float* p = acc1 + (long long)d * 48 + q * 4;
    atomic_add_f32(p + 0, val.x);
    atomic_add_f32(p + 1, val.y);
    atomic_add_f32(p + 2, val.z);
    atomic_add_f32(p + 3, val.w);
}

// ---- finish layer 1: y1 = relu(dinv * acc1 + b1) ----------------------------
__global__ void k_finish1(const float* __restrict__ acc1, const float* __restrict__ dinv,
                          const float* __restrict__ b1, float* __restrict__ y1, int n) {
    int t = blockIdx.x * blockDim.x + threadIdx.x;
    int v = t / 48, c = t % 48;
    if (v >= n) return;
    float val = fmaf(dinv[v], acc1[t], b1[c]);
    y1[t] = val > 0.f ? val : 0.f;
}

// ---- layer 2: g2 = dinv * (y1 @ W2), acc2 init = g2 -------------------------
__global__ void k_gemm2(const float* __restrict__ y1, const float* __restrict__ W2,
                        const float* __restrict__ dinv,
                        float* __restrict__ g2, float* __restrict__ acc2, int n) {
    __shared__ float Ws[48 * 32];
    for (int i = threadIdx.x; i < 48 * 32; i += blockDim.x) Ws[i] = W2[i];
    __syncthreads();
    int t = blockIdx.x * blockDim.x + threadIdx.x;
    int v = t / 32, j = t % 32;
    if (v >= n) return;
    const float* yr = y1 + (long long)v * 48;
    float s = 0.f;
#pragma unroll
    for (int c = 0; c < 48; ++c) s = fmaf(yr[c], Ws[c * 32 + j], s);
    s *= dinv[v];
    g2[t] = s;
    acc2[t] = s;
}

// ---- scatter layer 2: acc2[dst] += g2[src], 8 quads per edge ----------------
__global__ void k_scatter2(const int* __restrict__ src, const int* __restrict__ dst,
                           const float* __restrict__ g2, float* __restrict__ acc2, int E) {
    long long t = (long long)blockIdx.x * blockDim.x + threadIdx.x;
    int e = (int)(t / 8), q = (int)(t % 8);
    if (e >= E) return;
    int s = src[e], d = dst[e];
    float4 val = *reinterpret_cast<const float4*>(g2 + (long long)s * 32 + q * 4);
    float* p = acc2 + (long long)d * 32 + q * 4;
    atomic_add_f32(p + 0, val.x);
    atomic_add_f32(p + 1, val.y);
    atomic_add_f32(p + 2, val.z);
    atomic_add_f32(p + 3, val.w);
}

// ---- finish layer 2: y2 = relu(dinv * acc2 + b2) ----------------------------
__global__ void k_finish2(const float* __restrict__ acc2, const float* __restrict__ dinv,
                          const float* __restrict__ b2, float* __restrict__ y2, int n) {
    int t = blockIdx.x * blockDim.x + threadIdx.x;
    int v = t / 32, j = t % 32;
    if (v >= n) return;
    float val = fmaf(dinv[v], acc2[t], b2[j]);
    y2[t] = val > 0.f ? val : 0.f;
}

// ---- fc: out = y2 @ Wfc + bfc ----------------------------------------------
__global__ void k_fc(const float* __restrict__ y2, const float* __restrict__ Wfc,
                     const float* __restrict__ bfc, float* __restrict__ out, int n) {
    __shared__ float Ws[32 * 16];
    __shared__ float bs[16];
    for (int i = threadIdx.x; i < 32 * 16; i += blockDim.x) Ws[i] = Wfc[i];
    if (threadIdx.x < 16) bs[threadIdx.x] = bfc[threadIdx.x];
    __syncthreads();
    int t = blockIdx.x * blockDim.x + threadIdx.x;
    int v = t / 16, o = t % 16;
    if (v >= n) return;
    const float* yr = y2 + (long long)v * 32;
    float s = bs[o];
#pragma unroll
    for (int j = 0; j < 32; ++j) s = fmaf(yr[j], Ws[j * 16 + o], s);
    out[t] = s;
}

static inline int nblk(long long threads) { return (int)((threads + TPB - 1) / TPB); }

extern "C" void kernel_launch(void* const* d_in, const int* in_sizes, int n_in,
                              void* d_out, int out_size, void* d_ws, size_t ws_size,
                              hipStream_t stream) {
    const float* x   = (const float*)d_in[0];
    const int*  eidx = (const int*)d_in[1];
    const float* W1  = (const float*)d_in[2];
    const float* b1  = (const float*)d_in[3];
    const float* W2  = (const float*)d_in[4];
    const float* b2  = (const float*)d_in[5];
    const float* Wfc = (const float*)d_in[6];
    const float* bfc = (const float*)d_in[7];
    float* out = (float*)d_out;

    const int N = in_sizes[0] / 16;
    const int E = in_sizes[1] / 2;
    const int* src = eidx;
    const int* dst = eidx + E;

    float* ws   = (float*)d_ws;
    float* dinv = ws;                 // [N]   degree -> rsqrt(degree)
    float* bufA = dinv + N;           // [48N] g1, later y1
    float* bufB = bufA + 48LL * N;    // [48N] acc1
    float* bufC = bufB + 48LL * N;    // [32N] g2, later y2
    float* bufD = bufC + 32LL * N;    // [32N] acc2

    k_deg_init<<<nblk(N), TPB, 0, stream>>>(dinv, N);
    k_deg_count<<<nblk(E), TPB, 0, stream>>>(dst, dinv, E);
    k_rsqrt<<<nblk(N), TPB, 0, stream>>>(dinv, N);

    k_gemm1<<<nblk(48LL * N), TPB, 0, stream>>>(x, W1, dinv, bufA, bufB, N);
    k_scatter1<<<nblk(12LL * E), TPB, 0, stream>>>(src, dst, bufA, bufB, E);
    k_finish1<<<nblk(48LL * N), TPB, 0, stream>>>(bufB, dinv, b1, bufA, N);

    k_gemm2<<<nblk(32LL * N), TPB, 0, stream>>>(bufA, W2, dinv, bufC, bufD, N);
    k_scatter2<<<nblk(8LL * E), TPB, 0, stream>>>(src, dst, bufC, bufD, E);
    k_finish2<<<nblk(32LL * N), TPB, 0, stream>>>(bufD, dinv, b2, bufC, N);

    k_fc<<<nblk(16LL * N), TPB, 0, stream>>>(bufC, Wfc, bfc, out, N);
}

// Round 4
// 826.744 us; speedup vs baseline: 4.3125x; 4.3125x over previous
//
#include <hip/hip_runtime.h>

#define TPB 256

// ---- CSR build --------------------------------------------------------------
__global__ void k_zero(int* __restrict__ p, int n) {
    int i = blockIdx.x * blockDim.x + threadIdx.x;
    if (i < n) p[i] = 0;
}

__global__ void k_count(const int* __restrict__ dst, int* __restrict__ counts, int E) {
    int e = blockIdx.x * blockDim.x + threadIdx.x;
    if (e < E) atomicAdd(&counts[dst[e]], 1);
}

// single-block exclusive scan of counts -> row_start (+cursor copy, +dinv)
__global__ void k_scan(const int* __restrict__ counts, int* __restrict__ row_start,
                       int* __restrict__ cursor, float* __restrict__ dinv, int n) {
    __shared__ int wsum[16];
    __shared__ int s_carry;
    if (threadIdx.x == 0) s_carry = 0;
    __syncthreads();
    const int lane = threadIdx.x & 63;
    const int wid  = threadIdx.x >> 6;
    for (int base = 0; base < n; base += 1024) {
        int i = base + (int)threadIdx.x;
        int v = (i < n) ? counts[i] : 0;
        int ws = v;
#pragma unroll
        for (int off = 1; off < 64; off <<= 1) {
            int t = __shfl_up(ws, off, 64);
            if (lane >= off) ws += t;
        }
        if (lane == 63) wsum[wid] = ws;
        __syncthreads();
        if (wid == 0) {
            int x = (lane < 16) ? wsum[lane] : 0;
#pragma unroll
            for (int off = 1; off < 16; off <<= 1) {
                int t = __shfl_up(x, off, 64);
                if (lane >= off) x += t;
            }
            if (lane < 16) wsum[lane] = x;
        }
        __syncthreads();
        int block_incl = ws + (wid > 0 ? wsum[wid - 1] : 0);
        int carry = s_carry;
        if (i < n) {
            int rs = carry + block_incl - v;   // exclusive prefix
            row_start[i] = rs;
            cursor[i]    = rs;
            dinv[i]      = rsqrtf((float)(v + 1));   // +1 self-loop
        }
        __syncthreads();
        if (threadIdx.x == 1023) s_carry = carry + block_incl;
        __syncthreads();
    }
    if (threadIdx.x == 0) row_start[n] = s_carry;
}

__global__ void k_build(const int* __restrict__ src, const int* __restrict__ dst,
                        int* __restrict__ cursor, int* __restrict__ csr_src, int E) {
    int e = blockIdx.x * blockDim.x + threadIdx.x;
    if (e >= E) return;
    int pos = atomicAdd(&cursor[dst[e]], 1);
    csr_src[pos] = src[e];
}

// ---- g = dinv * (x @ W) -----------------------------------------------------
__global__ void k_gemm1(const float* __restrict__ x, const float* __restrict__ W1,
                        const float* __restrict__ dinv, float* __restrict__ g1, int n) {
    __shared__ float Ws[16 * 48];
    for (int i = threadIdx.x; i < 16 * 48; i += blockDim.x) Ws[i] = W1[i];
    __syncthreads();
    int t = blockIdx.x * blockDim.x + threadIdx.x;
    int v = t / 48, c = t % 48;
    if (v >= n) return;
    const float* xr = x + (long long)v * 16;
    float s = 0.f;
#pragma unroll
    for (int k = 0; k < 16; ++k) s = fmaf(xr[k], Ws[k * 48 + c], s);
    g1[t] = s * dinv[v];
}

__global__ void k_gemm2(const float* __restrict__ y1, const float* __restrict__ W2,
                        const float* __restrict__ dinv, float* __restrict__ g2, int n) {
    __shared__ float Ws[48 * 32];
    for (int i = threadIdx.x; i < 48 * 32; i += blockDim.x) Ws[i] = W2[i];
    __syncthreads();
    int t = blockIdx.x * blockDim.x + threadIdx.x;
    int v = t / 32, j = t % 32;
    if (v >= n) return;
    const float* yr = y1 + (long long)v * 48;
    float s = 0.f;
#pragma unroll
    for (int c = 0; c < 48; ++c) s = fmaf(yr[c], Ws[c * 32 + j], s);
    g2[t] = s * dinv[v];
}

// ---- fused gather + norm + bias + relu: y = relu(dinv*(g[v] + sum g[s]) + b)
template <int C>
__global__ void k_gather(const float* __restrict__ g, const int* __restrict__ row_start,
                         const int* __restrict__ csr_src, const float* __restrict__ dinv,
                         const float* __restrict__ bias, float* __restrict__ y, int n) {
    constexpr int Q = C / 4;
    int t = blockIdx.x * blockDim.x + threadIdx.x;
    int v = t / Q, q = t % Q;
    if (v >= n) return;
    int beg = row_start[v], end = row_start[v + 1];
    const float4* gq = reinterpret_cast<const float4*>(g);
    float4 acc = gq[(long long)v * Q + q];          // self-loop term
    for (int j = beg; j < end; ++j) {
        int s = csr_src[j];
        float4 m = gq[(long long)s * Q + q];
        acc.x += m.x; acc.y += m.y; acc.z += m.z; acc.w += m.w;
    }
    float di = dinv[v];
    float4 b4 = reinterpret_cast<const float4*>(bias)[q];
    float4 o;
    o.x = fmaxf(fmaf(di, acc.x, b4.x), 0.f);
    o.y = fmaxf(fmaf(di, acc.y, b4.y), 0.f);
    o.z = fmaxf(fmaf(di, acc.z, b4.z), 0.f);
    o.w = fmaxf(fmaf(di, acc.w, b4.w), 0.f);
    reinterpret_cast<float4*>(y)[(long long)v * Q + q] = o;
}

// ---- fc: out = y2 @ Wfc + bfc ----------------------------------------------
__global__ void k_fc(const float* __restrict__ y2, const float* __restrict__ Wfc,
                     const float* __restrict__ bfc, float* __restrict__ out, int n) {
    __shared__ float Ws[32 * 16];
    __shared__ float bs[16];
    for (int i = threadIdx.x; i < 32 * 16; i += blockDim.x) Ws[i] = Wfc[i];
    if (threadIdx.x < 16) bs[threadIdx.x] = bfc[threadIdx.x];
    __syncthreads();
    int t = blockIdx.x * blockDim.x + threadIdx.x;
    int v = t / 16, o = t % 16;
    if (v >= n) return;
    const float* yr = y2 + (long long)v * 32;
    float s = bs[o];
#pragma unroll
    for (int j = 0; j < 32; ++j) s = fmaf(yr[j], Ws[j * 16 + o], s);
    out[t] = s;
}

static inline int nblk(long long threads) { return (int)((threads + TPB - 1) / TPB); }

extern "C" void kernel_launch(void* const* d_in, const int* in_sizes, int n_in,
                              void* d_out, int out_size, void* d_ws, size_t ws_size,
                              hipStream_t stream) {
    const float* x   = (const float*)d_in[0];
    const int*  eidx = (const int*)d_in[1];
    const float* W1  = (const float*)d_in[2];
    const float* b1  = (const float*)d_in[3];
    const float* W2  = (const float*)d_in[4];
    const float* b2  = (const float*)d_in[5];
    const float* Wfc = (const float*)d_in[6];
    const float* bfc = (const float*)d_in[7];
    float* out = (float*)d_out;

    const int N = in_sizes[0] / 16;
    const int E = in_sizes[1] / 2;
    const int* src = eidx;
    const int* dst = eidx + E;

    // workspace layout
    float* fws  = (float*)d_ws;
    float* dinv = fws;                    // [N]
    float* g1   = dinv + N;               // [48N]
    float* y1   = g1 + 48LL * N;          // [48N]
    float* g2   = y1 + 48LL * N;          // [32N]
    float* y2   = g2 + 32LL * N;          // [32N]
    int* iws       = (int*)(y2 + 32LL * N);
    int* counts    = iws;                 // [N]
    int* row_start = counts + N;          // [N+1]
    int* cursor    = row_start + N + 1;   // [N]
    int* csr_src   = cursor + N;          // [E]

    // CSR build + degrees
    k_zero <<<nblk(N), TPB, 0, stream>>>(counts, N);
    k_count<<<nblk(E), TPB, 0, stream>>>(dst, counts, E);
    k_scan <<<1, 1024, 0, stream>>>(counts, row_start, cursor, dinv, N);
    k_build<<<nblk(E), TPB, 0, stream>>>(src, dst, cursor, csr_src, E);

    // layer 1
    k_gemm1<<<nblk(48LL * N), TPB, 0, stream>>>(x, W1, dinv, g1, N);
    k_gather<48><<<nblk(12LL * N), TPB, 0, stream>>>(g1, row_start, csr_src, dinv, b1, y1, N);

    // layer 2
    k_gemm2<<<nblk(32LL * N), TPB, 0, stream>>>(y1, W2, dinv, g2, N);
    k_gather<32><<<nblk(8LL * N), TPB, 0, stream>>>(g2, row_start, csr_src, dinv, b2, y2, N);

    // fc
    k_fc<<<nblk(16LL * N), TPB, 0, stream>>>(y2, Wfc, bfc, out, N);
}

// Round 6
// 714.666 us; speedup vs baseline: 4.9888x; 1.1568x over previous
//
#include <hip/hip_runtime.h>

#define TPB 256

// ---- CSR build --------------------------------------------------------------
__global__ void k_zero(int* __restrict__ p, int n) {
    int i = blockIdx.x * blockDim.x + threadIdx.x;
    if (i < n) p[i] = 0;
}

// 4 independent edges per thread for MLP
__global__ void k_count(const int* __restrict__ dst, int* __restrict__ counts, int E, int T) {
    int t = blockIdx.x * blockDim.x + threadIdx.x;
    int e0 = t, e1 = t + T, e2 = t + 2 * T, e3 = t + 3 * T;
    int d0 = 0, d1 = 0, d2 = 0, d3 = 0;
    if (e0 < E) d0 = dst[e0];
    if (e1 < E) d1 = dst[e1];
    if (e2 < E) d2 = dst[e2];
    if (e3 < E) d3 = dst[e3];
    if (e0 < E) atomicAdd(&counts[d0], 1);
    if (e1 < E) atomicAdd(&counts[d1], 1);
    if (e2 < E) atomicAdd(&counts[d2], 1);
    if (e3 < E) atomicAdd(&counts[d3], 1);
}

// single-block exclusive scan of counts -> row_start (+cursor copy, +dinv)
__global__ void k_scan(const int* __restrict__ counts, int* __restrict__ row_start,
                       int* __restrict__ cursor, float* __restrict__ dinv, int n) {
    __shared__ int wsum[16];
    __shared__ int s_carry;
    if (threadIdx.x == 0) s_carry = 0;
    __syncthreads();
    const int lane = threadIdx.x & 63;
    const int wid  = threadIdx.x >> 6;
    for (int base = 0; base < n; base += 1024) {
        int i = base + (int)threadIdx.x;
        int v = (i < n) ? counts[i] : 0;
        int ws = v;
#pragma unroll
        for (int off = 1; off < 64; off <<= 1) {
            int t = __shfl_up(ws, off, 64);
            if (lane >= off) ws += t;
        }
        if (lane == 63) wsum[wid] = ws;
        __syncthreads();
        if (wid == 0) {
            int x = (lane < 16) ? wsum[lane] : 0;
#pragma unroll
            for (int off = 1; off < 16; off <<= 1) {
                int t = __shfl_up(x, off, 64);
                if (lane >= off) x += t;
            }
            if (lane < 16) wsum[lane] = x;
        }
        __syncthreads();
        int block_incl = ws + (wid > 0 ? wsum[wid - 1] : 0);
        int carry = s_carry;
        if (i < n) {
            int rs = carry + block_incl - v;   // exclusive prefix
            row_start[i] = rs;
            cursor[i]    = rs;
            dinv[i]      = rsqrtf((float)(v + 1));   // +1 self-loop
        }
        __syncthreads();
        if (threadIdx.x == 1023) s_carry = carry + block_incl;
        __syncthreads();
    }
    if (threadIdx.x == 0) row_start[n] = s_carry;
}

// counting-sort placement, 4 independent edges per thread
__global__ void k_build(const int* __restrict__ src, const int* __restrict__ dst,
                        int* __restrict__ cursor, int* __restrict__ csr_src, int E, int T) {
    int t = blockIdx.x * blockDim.x + threadIdx.x;
    int e0 = t, e1 = t + T, e2 = t + 2 * T, e3 = t + 3 * T;
    int d0 = 0, d1 = 0, d2 = 0, d3 = 0, s0 = 0, s1 = 0, s2 = 0, s3 = 0;
    if (e0 < E) { d0 = dst[e0]; s0 = src[e0]; }
    if (e1 < E) { d1 = dst[e1]; s1 = src[e1]; }
    if (e2 < E) { d2 = dst[e2]; s2 = src[e2]; }
    if (e3 < E) { d3 = dst[e3]; s3 = src[e3]; }
    int p0 = 0, p1 = 0, p2 = 0, p3 = 0;
    if (e0 < E) p0 = atomicAdd(&cursor[d0], 1);
    if (e1 < E) p1 = atomicAdd(&cursor[d1], 1);
    if (e2 < E) p2 = atomicAdd(&cursor[d2], 1);
    if (e3 < E) p3 = atomicAdd(&cursor[d3], 1);
    if (e0 < E) csr_src[p0] = s0;
    if (e1 < E) csr_src[p1] = s1;
    if (e2 < E) csr_src[p2] = s2;
    if (e3 < E) csr_src[p3] = s3;
}

// ---- xs = dinv[v] * x[v]  (prescale, 16ch) ---------------------------------
__global__ void k_prescale(const float* __restrict__ x, const float* __restrict__ dinv,
                           float* __restrict__ xs, int n) {
    int t = blockIdx.x * blockDim.x + threadIdx.x;   // n*4 quads
    int v = t >> 2;
    if (v >= n) return;
    float di = dinv[v];
    float4 a = reinterpret_cast<const float4*>(x)[t];
    a.x *= di; a.y *= di; a.z *= di; a.w *= di;
    reinterpret_cast<float4*>(xs)[t] = a;
}

// ---- fused gather: acc = g[v] + sum g[s]; out = di*acc (+bias,relu if EPI) --
template <int C, bool EPI>
__global__ void k_gather(const float* __restrict__ g, const int* __restrict__ row_start,
                         const int* __restrict__ csr_src, const float* __restrict__ dinv,
                         const float* __restrict__ bias, float* __restrict__ y, int n) {
    constexpr int Q = C / 4;
    int t = blockIdx.x * blockDim.x + threadIdx.x;
    int v = t / Q, q = t % Q;
    if (v >= n) return;
    int beg = row_start[v], end = row_start[v + 1];
    const float4* gq = reinterpret_cast<const float4*>(g);
    float4 acc = gq[(long long)v * Q + q];          // self-loop term
    for (int j = beg; j < end; ++j) {
        int s = csr_src[j];
        float4 m = gq[(long long)s * Q + q];
        acc.x += m.x; acc.y += m.y; acc.z += m.z; acc.w += m.w;
    }
    float di = dinv[v];
    float4 o;
    if (EPI) {
        float4 b4 = reinterpret_cast<const float4*>(bias)[q];
        o.x = fmaxf(fmaf(di, acc.x, b4.x), 0.f);
        o.y = fmaxf(fmaf(di, acc.y, b4.y), 0.f);
        o.z = fmaxf(fmaf(di, acc.z, b4.z), 0.f);
        o.w = fmaxf(fmaf(di, acc.w, b4.w), 0.f);
    } else {
        o.x = di * acc.x; o.y = di * acc.y; o.z = di * acc.z; o.w = di * acc.w;
    }
    reinterpret_cast<float4*>(y)[(long long)v * Q + q] = o;
}

// ---- y1 = relu(agg1 @ W1 + b1), 16 -> 48 ------------------------------------
__global__ void k_lin1(const float* __restrict__ agg1, const float* __restrict__ W1,
                       const float* __restrict__ b1, float* __restrict__ y1, int n) {
    __shared__ float Ws[16 * 48];
    __shared__ float bs[48];
    for (int i = threadIdx.x; i < 16 * 48; i += blockDim.x) Ws[i] = W1[i];
    if (threadIdx.x < 48) bs[threadIdx.x] = b1[threadIdx.x];
    __syncthreads();
    int t = blockIdx.x * blockDim.x + threadIdx.x;
    int v = t / 48, c = t % 48;
    if (v >= n) return;
    const float* ar = agg1 + (long long)v * 16;
    float s = bs[c];
#pragma unroll
    for (int k = 0; k < 16; ++k) s = fmaf(ar[k], Ws[k * 48 + c], s);
    y1[t] = s > 0.f ? s : 0.f;
}

// ---- g2 = dinv * (y1 @ W2), 48 -> 32 ----------------------------------------
__global__ void k_gemm2(const float* __restrict__ y1, const float* __restrict__ W2,
                        const float* __restrict__ dinv, float* __restrict__ g2, int n) {
    __shared__ float Ws[48 * 32];
    for (int i = threadIdx.x; i < 48 * 32; i += blockDim.x) Ws[i] = W2[i];
    __syncthreads();
    int t = blockIdx.x * blockDim.x + threadIdx.x;
    int v = t / 32, j = t % 32;
    if (v >= n) return;
    const float* yr = y1 + (long long)v * 48;
    float s = 0.f;
#pragma unroll
    for (int c = 0; c < 48; ++c) s = fmaf(yr[c], Ws[c * 32 + j], s);
    g2[t] = s * dinv[v];
}

// ---- fc: out = y2 @ Wfc + bfc ----------------------------------------------
__global__ void k_fc(const float* __restrict__ y2, const float* __restrict__ Wfc,
                     const float* __restrict__ bfc, float* __restrict__ out, int n) {
    __shared__ float Ws[32 * 16];
    __shared__ float bs[16];
    for (int i = threadIdx.x; i < 32 * 16; i += blockDim.x) Ws[i] = Wfc[i];
    if (threadIdx.x < 16) bs[threadIdx.x] = bfc[threadIdx.x];
    __syncthreads();
    int t = blockIdx.x * blockDim.x + threadIdx.x;
    int v = t / 16, o = t % 16;
    if (v >= n) return;
    const float* yr = y2 + (long long)v * 32;
    float s = bs[o];
#pragma unroll
    for (int j = 0; j < 32; ++j) s = fmaf(yr[j], Ws[j * 16 + o], s);
    out[t] = s;
}

static inline int nblk(long long threads) { return (int)((threads + TPB - 1) / TPB); }

extern "C" void kernel_launch(void* const* d_in, const int* in_sizes, int n_in,
                              void* d_out, int out_size, void* d_ws, size_t ws_size,
                              hipStream_t stream) {
    const float* x   = (const float*)d_in[0];
    const int*  eidx = (const int*)d_in[1];
    const float* W1  = (const float*)d_in[2];
    const float* b1  = (const float*)d_in[3];
    const float* W2  = (const float*)d_in[4];
    const float* b2  = (const float*)d_in[5];
    const float* Wfc = (const float*)d_in[6];
    const float* bfc = (const float*)d_in[7];
    float* out = (float*)d_out;

    const int N = in_sizes[0] / 16;
    const int E = in_sizes[1] / 2;
    const int* src = eidx;
    const int* dst = eidx + E;

    // workspace layout (N % 4 == 0 keeps float4 alignment for all sub-buffers)
    float* fws  = (float*)d_ws;
    float* dinv = fws;                    // [N]
    float* xs   = dinv + N;               // [16N]  dinv*x
    float* agg1 = xs + 16LL * N;          // [16N]
    float* y1   = agg1 + 16LL * N;        // [48N]
    float* g2   = y1 + 48LL * N;          // [32N]
    float* y2   = g2 + 32LL * N;          // [32N]
    int* iws       = (int*)(y2 + 32LL * N);
    int* counts    = iws;                 // [N]
    int* row_start = counts + N;          // [N+1]
    int* cursor    = row_start + N + 1;   // [N]
    int* csr_src   = cursor + N;          // [E]

    const int T = (E + 3) / 4;            // edges per MLP slice

    // CSR build + degrees
    k_zero <<<nblk(N), TPB, 0, stream>>>(counts, N);
    k_count<<<nblk(T), TPB, 0, stream>>>(dst, counts, E, T);
    k_scan <<<1, 1024, 0, stream>>>(counts, row_start, cursor, dinv, N);
    k_build<<<nblk(T), TPB, 0, stream>>>(src, dst, cursor, csr_src, E, T);

    // layer 1: aggregate-first (16ch), then transform
    k_prescale<<<nblk(4LL * N), TPB, 0, stream>>>(x, dinv, xs, N);
    k_gather<16, false><<<nblk(4LL * N), TPB, 0, stream>>>(xs, row_start, csr_src, dinv, nullptr, agg1, N);
    k_lin1<<<nblk(48LL * N), TPB, 0, stream>>>(agg1, W1, b1, y1, N);

    // layer 2: transform-first (32ch)
    k_gemm2<<<nblk(32LL * N), TPB, 0, stream>>>(y1, W2, dinv, g2, N);
    k_gather<32, true><<<nblk(8LL * N), TPB, 0, stream>>>(g2, row_start, csr_src, dinv, b2, y2, N);

    // fc
    k_fc<<<nblk(16LL * N), TPB, 0, stream>>>(y2, Wfc, bfc, out, N);
}

// Round 9
// 436.856 us; speedup vs baseline: 8.1613x; 1.6359x over previous
//
#include <hip/hip_runtime.h>

#define TPB 256
#define G_BITS 8
#define G_SZ 256            // nodes per bucket (pow2)
#define B_CAP 10240         // pair capacity per bucket (mean ~8184, +23 sigma)
#define KA_TPB 512
#define KA_EPT 16           // edges per thread in kA
#define OV_CAP 8192

// ---- zero bucket_fill + ov_cnt ---------------------------------------------
__global__ void k_zerofill(int* __restrict__ bucket_fill, int* __restrict__ ov_cnt, int NB) {
    int i = threadIdx.x;
    for (; i < NB; i += blockDim.x) bucket_fill[i] = 0;
    if (threadIdx.x == 0) *ov_cnt = 0;
}

// ---- pass A: bin edges into per-bucket regions as packed u32 ---------------
// pack = (local_dst << 20) | src   (src < 2^20)
__global__ void kA_bin(const int* __restrict__ src, const int* __restrict__ dst,
                       int* __restrict__ bucket_fill, unsigned* __restrict__ pairs,
                       int* __restrict__ ov_cnt, int2* __restrict__ ov_pairs,
                       int E, int NB) {
    __shared__ int hist[512];
    __shared__ int cur[512];
    const int base = blockIdx.x * (KA_TPB * KA_EPT);
    for (int i = threadIdx.x; i < NB; i += KA_TPB) hist[i] = 0;
    __syncthreads();
    int s[KA_EPT], d[KA_EPT];
#pragma unroll
    for (int k = 0; k < KA_EPT; ++k) {
        int e = base + (int)threadIdx.x + k * KA_TPB;
        if (e < E) { s[k] = src[e]; d[k] = dst[e]; }
        else       { s[k] = -1;     d[k] = 0;      }
    }
#pragma unroll
    for (int k = 0; k < KA_EPT; ++k)
        if (s[k] >= 0) atomicAdd(&hist[d[k] >> G_BITS], 1);
    __syncthreads();
    for (int b = threadIdx.x; b < NB; b += KA_TPB) {
        int h = hist[b];
        int start = h ? atomicAdd(&bucket_fill[b], h) : 0;
        cur[b] = b * B_CAP + start;
    }
    __syncthreads();
#pragma unroll
    for (int k = 0; k < KA_EPT; ++k) {
        if (s[k] < 0) continue;
        int b = d[k] >> G_BITS;
        int slot = atomicAdd(&cur[b], 1);
        if (slot < (b + 1) * B_CAP) {
            pairs[slot] = ((unsigned)(d[k] & (G_SZ - 1)) << 20) | (unsigned)s[k];
        } else {                                  // ~never: defensive overflow
            int o = atomicAdd(ov_cnt, 1);
            if (o < OV_CAP) ov_pairs[o] = make_int2(s[k], d[k]);
        }
    }
}

// ---- per-bucket histogram -> counts (no global atomics) --------------------
__global__ void kC_hist(const unsigned* __restrict__ pairs, const int* __restrict__ bucket_fill,
                        int* __restrict__ counts, int N) {
    __shared__ int hist[G_SZ];
    const int b = blockIdx.x;
    for (int i = threadIdx.x; i < G_SZ; i += TPB) hist[i] = 0;
    __syncthreads();
    int fill = bucket_fill[b]; if (fill > B_CAP) fill = B_CAP;
    const unsigned* p = pairs + (long long)b * B_CAP;
    for (int j = threadIdx.x; j < fill; j += TPB)
        atomicAdd(&hist[p[j] >> 20], 1);
    __syncthreads();
    const int lo = b << G_BITS;
    for (int i = threadIdx.x; i < G_SZ; i += TPB)
        if (lo + i < N) counts[lo + i] = hist[i];
}

__global__ void kC_ov(const int* __restrict__ ov_cnt, const int2* __restrict__ ov_pairs,
                      int* __restrict__ counts) {
    int t = blockIdx.x * blockDim.x + threadIdx.x;
    int n = *ov_cnt; if (n > OV_CAP) n = OV_CAP;
    if (t < n) atomicAdd(&counts[ov_pairs[t].y], 1);
}

// single-block exclusive scan of counts -> row_start (+cursor copy, +dinv)
__global__ void k_scan(const int* __restrict__ counts, int* __restrict__ row_start,
                       int* __restrict__ cursor, float* __restrict__ dinv, int n) {
    __shared__ int wsum[16];
    __shared__ int s_carry;
    if (threadIdx.x == 0) s_carry = 0;
    __syncthreads();
    const int lane = threadIdx.x & 63;
    const int wid  = threadIdx.x >> 6;
    for (int base = 0; base < n; base += 1024) {
        int i = base + (int)threadIdx.x;
        int v = (i < n) ? counts[i] : 0;
        int ws = v;
#pragma unroll
        for (int off = 1; off < 64; off <<= 1) {
            int t = __shfl_up(ws, off, 64);
            if (lane >= off) ws += t;
        }
        if (lane == 63) wsum[wid] = ws;
        __syncthreads();
        if (wid == 0) {
            int x = (lane < 16) ? wsum[lane] : 0;
#pragma unroll
            for (int off = 1; off < 16; off <<= 1) {
                int t = __shfl_up(x, off, 64);
                if (lane >= off) x += t;
            }
            if (lane < 16) wsum[lane] = x;
        }
        __syncthreads();
        int block_incl = ws + (wid > 0 ? wsum[wid - 1] : 0);
        int carry = s_carry;
        if (i < n) {
            int rs = carry + block_incl - v;   // exclusive prefix
            row_start[i] = rs;
            cursor[i]    = rs;
            dinv[i]      = rsqrtf((float)(v + 1));   // +1 self-loop
        }
        __syncthreads();
        if (threadIdx.x == 1023) s_carry = carry + block_incl;
        __syncthreads();
    }
    if (threadIdx.x == 0) row_start[n] = s_carry;
}

// overflow placement (before kB_place; advances global cursor) ----------------
__global__ void kB_ov(const int* __restrict__ ov_cnt, const int2* __restrict__ ov_pairs,
                      int* __restrict__ cursor, int* __restrict__ csr_src) {
    int t = blockIdx.x * blockDim.x + threadIdx.x;
    int n = *ov_cnt; if (n > OV_CAP) n = OV_CAP;
    if (t < n) {
        int pos = atomicAdd(&cursor[ov_pairs[t].y], 1);
        csr_src[pos] = ov_pairs[t].x;
    }
}

// ---- pass B: per-bucket placement; csr writes confined to ~25KB window -----
__global__ void kB_place(const unsigned* __restrict__ pairs, const int* __restrict__ bucket_fill,
                         const int* __restrict__ cursor, int* __restrict__ csr_src, int N) {
    __shared__ int cur[G_SZ];
    const int b = blockIdx.x;
    const int lo = b << G_BITS;
    for (int i = threadIdx.x; i < G_SZ; i += TPB)
        cur[i] = (lo + i < N) ? cursor[lo + i] : 0;
    __syncthreads();
    int fill = bucket_fill[b]; if (fill > B_CAP) fill = B_CAP;
    const unsigned* p = pairs + (long long)b * B_CAP;
    for (int j = threadIdx.x; j < fill; j += TPB) {
        unsigned v = p[j];
        int pos = atomicAdd(&cur[v >> 20], 1);
        csr_src[pos] = (int)(v & 0xFFFFFu);
    }
}

// ---- xs = dinv[v] * x[v]  (prescale, 16ch) ---------------------------------
__global__ void k_prescale(const float* __restrict__ x, const float* __restrict__ dinv,
                           float* __restrict__ xs, int n) {
    int t = blockIdx.x * blockDim.x + threadIdx.x;   // n*4 quads
    int v = t >> 2;
    if (v >= n) return;
    float di = dinv[v];
    float4 a = reinterpret_cast<const float4*>(x)[t];
    a.x *= di; a.y *= di; a.z *= di; a.w *= di;
    reinterpret_cast<float4*>(xs)[t] = a;
}

// ---- fused gather: acc = g[v] + sum g[s]; out = di*acc (+bias,relu if EPI) --
template <int C, bool EPI>
__global__ void k_gather(const float* __restrict__ g, const int* __restrict__ row_start,
                         const int* __restrict__ csr_src, const float* __restrict__ dinv,
                         const float* __restrict__ bias, float* __restrict__ y, int n) {
    constexpr int Q = C / 4;
    int t = blockIdx.x * blockDim.x + threadIdx.x;
    int v = t / Q, q = t % Q;
    if (v >= n) return;
    int beg = row_start[v], end = row_start[v + 1];
    const float4* gq = reinterpret_cast<const float4*>(g);
    float4 acc = gq[(long long)v * Q + q];          // self-loop term
    for (int j = beg; j < end; ++j) {
        int s = csr_src[j];
        float4 m = gq[(long long)s * Q + q];
        acc.x += m.x; acc.y += m.y; acc.z += m.z; acc.w += m.w;
    }
    float di = dinv[v];
    float4 o;
    if (EPI) {
        float4 b4 = reinterpret_cast<const float4*>(bias)[q];
        o.x = fmaxf(fmaf(di, acc.x, b4.x), 0.f);
        o.y = fmaxf(fmaf(di, acc.y, b4.y), 0.f);
        o.z = fmaxf(fmaf(di, acc.z, b4.z), 0.f);
        o.w = fmaxf(fmaf(di, acc.w, b4.w), 0.f);
    } else {
        o.x = di * acc.x; o.y = di * acc.y; o.z = di * acc.z; o.w = di * acc.w;
    }
    reinterpret_cast<float4*>(y)[(long long)v * Q + q] = o;
}

// ---- y1 = relu(agg1 @ W1 + b1), 16 -> 48 ------------------------------------
__global__ void k_lin1(const float* __restrict__ agg1, const float* __restrict__ W1,
                       const float* __restrict__ b1, float* __restrict__ y1, int n) {
    __shared__ float Ws[16 * 48];
    __shared__ float bs[48];
    for (int i = threadIdx.x; i < 16 * 48; i += blockDim.x) Ws[i] = W1[i];
    if (threadIdx.x < 48) bs[threadIdx.x] = b1[threadIdx.x];
    __syncthreads();
    int t = blockIdx.x * blockDim.x + threadIdx.x;
    int v = t / 48, c = t % 48;
    if (v >= n) return;
    const float* ar = agg1 + (long long)v * 16;
    float s = bs[c];
#pragma unroll
    for (int k = 0; k < 16; ++k) s = fmaf(ar[k], Ws[k * 48 + c], s);
    y1[t] = s > 0.f ? s : 0.f;
}

// ---- g2 = dinv * (y1 @ W2), 48 -> 32 ----------------------------------------
__global__ void k_gemm2(const float* __restrict__ y1, const float* __restrict__ W2,
                        const float* __restrict__ dinv, float* __restrict__ g2, int n) {
    __shared__ float Ws[48 * 32];
    for (int i = threadIdx.x; i < 48 * 32; i += blockDim.x) Ws[i] = W2[i];
    __syncthreads();
    int t = blockIdx.x * blockDim.x + threadIdx.x;
    int v = t / 32, j = t % 32;
    if (v >= n) return;
    const float* yr = y1 + (long long)v * 48;
    float s = 0.f;
#pragma unroll
    for (int c = 0; c < 48; ++c) s = fmaf(yr[c], Ws[c * 32 + j], s);
    g2[t] = s * dinv[v];
}

// ---- fc: out = y2 @ Wfc + bfc ----------------------------------------------
__global__ void k_fc(const float* __restrict__ y2, const float* __restrict__ Wfc,
                     const float* __restrict__ bfc, float* __restrict__ out, int n) {
    __shared__ float Ws[32 * 16];
    __shared__ float bs[16];
    for (int i = threadIdx.x; i < 32 * 16; i += blockDim.x) Ws[i] = Wfc[i];
    if (threadIdx.x < 16) bs[threadIdx.x] = bfc[threadIdx.x];
    __syncthreads();
    int t = blockIdx.x * blockDim.x + threadIdx.x;
    int v = t / 16, o = t % 16;
    if (v >= n) return;
    const float* yr = y2 + (long long)v * 32;
    float s = bs[o];
#pragma unroll
    for (int j = 0; j < 32; ++j) s = fmaf(yr[j], Ws[j * 16 + o], s);
    out[t] = s;
}

static inline int nblk(long long threads) { return (int)((threads + TPB - 1) / TPB); }

extern "C" void kernel_launch(void* const* d_in, const int* in_sizes, int n_in,
                              void* d_out, int out_size, void* d_ws, size_t ws_size,
                              hipStream_t stream) {
    const float* x   = (const float*)d_in[0];
    const int*  eidx = (const int*)d_in[1];
    const float* W1  = (const float*)d_in[2];
    const float* b1  = (const float*)d_in[3];
    const float* W2  = (const float*)d_in[4];
    const float* b2  = (const float*)d_in[5];
    const float* Wfc = (const float*)d_in[6];
    const float* bfc = (const float*)d_in[7];
    float* out = (float*)d_out;

    const int N = in_sizes[0] / 16;
    const int E = in_sizes[1] / 2;
    const int* src = eidx;
    const int* dst = eidx + E;
    const int NB = (N + G_SZ - 1) >> G_BITS;     // buckets (<= 512)

    // workspace layout
    float* fws  = (float*)d_ws;
    float* dinv = fws;                    // [N]
    float* xs   = dinv + N;               // [16N]  dinv*x
    float* agg1 = xs + 16LL * N;          // [16N]
    float* y1   = agg1 + 16LL * N;        // [48N]
    float* g2   = y1 + 48LL * N;          // [32N]
    float* y2   = g2 + 32LL * N;          // [32N]
    int* counts    = (int*)(y2 + 32LL * N);  // [N]
    int* row_start = counts + N;             // [N+1]
    int* cursor    = row_start + N + 1;      // [N]
    int* csr_src   = cursor + N;             // [E]
    unsigned* pairs  = (unsigned*)(csr_src + E);        // [NB*B_CAP]
    int* bucket_fill = (int*)(pairs + (long long)NB * B_CAP); // [NB]
    int* ov_cnt      = bucket_fill + NB;                // [1]
    uintptr_t pov = ((uintptr_t)(ov_cnt + 1) + 7) & ~(uintptr_t)7;
    int2* ov_pairs   = (int2*)pov;                      // [OV_CAP]

    // ---- CSR build (bucketed two-phase counting sort) ----
    k_zerofill<<<1, 512, 0, stream>>>(bucket_fill, ov_cnt, NB);
    kA_bin<<<(E + KA_TPB * KA_EPT - 1) / (KA_TPB * KA_EPT), KA_TPB, 0, stream>>>(
        src, dst, bucket_fill, pairs, ov_cnt, ov_pairs, E, NB);
    kC_hist<<<NB, TPB, 0, stream>>>(pairs, bucket_fill, counts, N);
    kC_ov<<<OV_CAP / TPB, TPB, 0, stream>>>(ov_cnt, ov_pairs, counts);
    k_scan<<<1, 1024, 0, stream>>>(counts, row_start, cursor, dinv, N);
    kB_ov<<<OV_CAP / TPB, TPB, 0, stream>>>(ov_cnt, ov_pairs, cursor, csr_src);
    kB_place<<<NB, TPB, 0, stream>>>(pairs, bucket_fill, cursor, csr_src, N);

    // ---- layer 1: aggregate-first (16ch), then transform ----
    k_prescale<<<nblk(4LL * N), TPB, 0, stream>>>(x, dinv, xs, N);
    k_gather<16, false><<<nblk(4LL * N), TPB, 0, stream>>>(xs, row_start, csr_src, dinv, nullptr, agg1, N);
    k_lin1<<<nblk(48LL * N), TPB, 0, stream>>>(agg1, W1, b1, y1, N);

    // ---- layer 2: transform-first (32ch) ----
    k_gemm2<<<nblk(32LL * N), TPB, 0, stream>>>(y1, W2, dinv, g2, N);
    k_gather<32, true><<<nblk(8LL * N), TPB, 0, stream>>>(g2, row_start, csr_src, dinv, b2, y2, N);

    // ---- fc ----
    k_fc<<<nblk(16LL * N), TPB, 0, stream>>>(y2, Wfc, bfc, out, N);
}

// Round 11
// 328.171 us; speedup vs baseline: 10.8642x; 1.3312x over previous
//
#include <hip/hip_runtime.h>

#define TPB 256
#define G_BITS 8
#define G_SZ 256            // nodes per bucket (pow2)
#define B_CAP 10240         // pair capacity per bucket (mean ~8184, +23 sigma)
#define KA_TPB 512
#define KA_EPT 16           // edges per thread in kA
#define OV_CAP 8192

// ---- zero bucket_fill + ov_cnt ---------------------------------------------
__global__ void k_zerofill(int* __restrict__ bucket_fill, int* __restrict__ ov_cnt, int NB) {
    int i = threadIdx.x;
    for (; i < NB; i += blockDim.x) bucket_fill[i] = 0;
    if (threadIdx.x == 0) *ov_cnt = 0;
}

// ---- pass A: bin edges into per-bucket regions as packed u32 ---------------
// pack = (local_dst << 20) | src   (src < 2^20)
__global__ void kA_bin(const int* __restrict__ src, const int* __restrict__ dst,
                       int* __restrict__ bucket_fill, unsigned* __restrict__ pairs,
                       int* __restrict__ ov_cnt, int2* __restrict__ ov_pairs,
                       int E, int NB) {
    __shared__ int hist[512];
    __shared__ int cur[512];
    const int base = blockIdx.x * (KA_TPB * KA_EPT);
    for (int i = threadIdx.x; i < NB; i += KA_TPB) hist[i] = 0;
    __syncthreads();
    int s[KA_EPT], d[KA_EPT];
#pragma unroll
    for (int k = 0; k < KA_EPT; ++k) {
        int e = base + (int)threadIdx.x + k * KA_TPB;
        if (e < E) { s[k] = src[e]; d[k] = dst[e]; }
        else       { s[k] = -1;     d[k] = 0;      }
    }
#pragma unroll
    for (int k = 0; k < KA_EPT; ++k)
        if (s[k] >= 0) atomicAdd(&hist[d[k] >> G_BITS], 1);
    __syncthreads();
    for (int b = threadIdx.x; b < NB; b += KA_TPB) {
        int h = hist[b];
        int start = h ? atomicAdd(&bucket_fill[b], h) : 0;
        cur[b] = b * B_CAP + start;
    }
    __syncthreads();
#pragma unroll
    for (int k = 0; k < KA_EPT; ++k) {
        if (s[k] < 0) continue;
        int b = d[k] >> G_BITS;
        int slot = atomicAdd(&cur[b], 1);
        if (slot < (b + 1) * B_CAP) {
            pairs[slot] = ((unsigned)(d[k] & (G_SZ - 1)) << 20) | (unsigned)s[k];
        } else {                                  // ~never: defensive overflow
            int o = atomicAdd(ov_cnt, 1);
            if (o < OV_CAP) ov_pairs[o] = make_int2(s[k], d[k]);
        }
    }
}

// ---- bucket-level scan: totals (placed + stored ov) -> bucket_base ---------
// Single block, 512 threads; NB <= 512 (N <= 131072).
__global__ void k_bscan(const int* __restrict__ bucket_fill,
                        const int* __restrict__ ov_cnt, const int2* __restrict__ ov_pairs,
                        int* __restrict__ bucket_base, int* __restrict__ row_start,
                        int NB, int N) {
    __shared__ int tot[512];
    __shared__ int wsum[8];
    const int i = threadIdx.x;
    int f = 0;
    if (i < NB) { f = bucket_fill[i]; if (f > B_CAP) f = B_CAP; }
    tot[i] = f;
    __syncthreads();
    int nov = *ov_cnt; if (nov > OV_CAP) nov = OV_CAP;
    for (int j = i; j < nov; j += 512)
        atomicAdd(&tot[ov_pairs[j].y >> G_BITS], 1);
    __syncthreads();
    int v = tot[i];
    const int lane = i & 63, wid = i >> 6;
    int incl = v;
#pragma unroll
    for (int off = 1; off < 64; off <<= 1) {
        int t = __shfl_up(incl, off, 64);
        if (lane >= off) incl += t;
    }
    if (lane == 63) wsum[wid] = incl;
    __syncthreads();
    int woff = 0;
    for (int w = 0; w < wid; ++w) woff += wsum[w];
    int ex = woff + incl - v;                 // exclusive prefix
    if (i < NB) bucket_base[i] = ex;
    if (i == NB - 1) { bucket_base[NB] = ex + v; row_start[N] = ex + v; }
}

// ---- per-bucket: hist -> local scan -> row_start/dinv -> place csr ---------
__global__ void kD_finish(const unsigned* __restrict__ pairs, const int* __restrict__ bucket_fill,
                          const int* __restrict__ bucket_base,
                          const int* __restrict__ ov_cnt, const int2* __restrict__ ov_pairs,
                          int* __restrict__ row_start, float* __restrict__ dinv,
                          int* __restrict__ csr_src, int N) {
    __shared__ int hist[G_SZ];
    __shared__ int cur[G_SZ];
    __shared__ int wsum[G_SZ / 64];
    const int b = blockIdx.x;
    const int lo = b << G_BITS;
    hist[threadIdx.x] = 0;                    // TPB == G_SZ
    __syncthreads();
    int fill = bucket_fill[b]; if (fill > B_CAP) fill = B_CAP;
    const unsigned* p = pairs + (long long)b * B_CAP;
    for (int j = threadIdx.x; j < fill; j += TPB)
        atomicAdd(&hist[p[j] >> 20], 1);
    int nov = *ov_cnt; if (nov > OV_CAP) nov = OV_CAP;
    for (int j = threadIdx.x; j < nov; j += TPB) {
        int d = ov_pairs[j].y;
        if ((d >> G_BITS) == b) atomicAdd(&hist[d & (G_SZ - 1)], 1);
    }
    __syncthreads();
    const int i = threadIdx.x;
    int v = hist[i];
    const int lane = i & 63, wid = i >> 6;
    int incl = v;
#pragma unroll
    for (int off = 1; off < 64; off <<= 1) {
        int t = __shfl_up(incl, off, 64);
        if (lane >= off) incl += t;
    }
    if (lane == 63) wsum[wid] = incl;
    __syncthreads();
    int woff = 0;
    for (int w = 0; w < wid; ++w) woff += wsum[w];
    int ex = bucket_base[b] + woff + incl - v;   // global exclusive prefix
    if (lo + i < N) {
        row_start[lo + i] = ex;
        dinv[lo + i] = rsqrtf((float)(v + 1));   // +1 self-loop
    }
    cur[i] = ex;
    __syncthreads();
    for (int j = threadIdx.x; j < fill; j += TPB) {
        unsigned pv = p[j];
        int pos = atomicAdd(&cur[pv >> 20], 1);
        csr_src[pos] = (int)(pv & 0xFFFFFu);
    }
    for (int j = threadIdx.x; j < nov; j += TPB) {
        int d = ov_pairs[j].y;
        if ((d >> G_BITS) == b) {
            int pos = atomicAdd(&cur[d & (G_SZ - 1)], 1);
            csr_src[pos] = ov_pairs[j].x;
        }
    }
}

// ---- xs = dinv[v] * x[v]  (prescale, 16ch) ---------------------------------
__global__ void k_prescale(const float* __restrict__ x, const float* __restrict__ dinv,
                           float* __restrict__ xs, int n) {
    int t = blockIdx.x * blockDim.x + threadIdx.x;   // n*4 quads
    int v = t >> 2;
    if (v >= n) return;
    float di = dinv[v];
    float4 a = reinterpret_cast<const float4*>(x)[t];
    a.x *= di; a.y *= di; a.z *= di; a.w *= di;
    reinterpret_cast<float4*>(xs)[t] = a;
}

// ---- fused gather: acc = g[v] + sum g[s]; out = di*acc (+bias,relu if EPI) --
template <int C, bool EPI>
__global__ void k_gather(const float* __restrict__ g, const int* __restrict__ row_start,
                         const int* __restrict__ csr_src, const float* __restrict__ dinv,
                         const float* __restrict__ bias, float* __restrict__ y, int n) {
    constexpr int Q = C / 4;
    int t = blockIdx.x * blockDim.x + threadIdx.x;
    int v = t / Q, q = t % Q;
    if (v >= n) return;
    int beg = row_start[v], end = row_start[v + 1];
    const float4* gq = reinterpret_cast<const float4*>(g);
    float4 acc = gq[(long long)v * Q + q];          // self-loop term
    for (int j = beg; j < end; ++j) {
        int s = csr_src[j];
        float4 m = gq[(long long)s * Q + q];
        acc.x += m.x; acc.y += m.y; acc.z += m.z; acc.w += m.w;
    }
    float di = dinv[v];
    float4 o;
    if (EPI) {
        float4 b4 = reinterpret_cast<const float4*>(bias)[q];
        o.x = fmaxf(fmaf(di, acc.x, b4.x), 0.f);
        o.y = fmaxf(fmaf(di, acc.y, b4.y), 0.f);
        o.z = fmaxf(fmaf(di, acc.z, b4.z), 0.f);
        o.w = fmaxf(fmaf(di, acc.w, b4.w), 0.f);
    } else {
        o.x = di * acc.x; o.y = di * acc.y; o.z = di * acc.z; o.w = di * acc.w;
    }
    reinterpret_cast<float4*>(y)[(long long)v * Q + q] = o;
}

// ---- y1 = relu(agg1 @ W1 + b1), 16 -> 48 ------------------------------------
__global__ void k_lin1(const float* __restrict__ agg1, const float* __restrict__ W1,
                       const float* __restrict__ b1, float* __restrict__ y1, int n) {
    __shared__ float Ws[16 * 48];
    __shared__ float bs[48];
    for (int i = threadIdx.x; i < 16 * 48; i += blockDim.x) Ws[i] = W1[i];
    if (threadIdx.x < 48) bs[threadIdx.x] = b1[threadIdx.x];
    __syncthreads();
    int t = blockIdx.x * blockDim.x + threadIdx.x;
    int v = t / 48, c = t % 48;
    if (v >= n) return;
    const float* ar = agg1 + (long long)v * 16;
    float s = bs[c];
#pragma unroll
    for (int k = 0; k < 16; ++k) s = fmaf(ar[k], Ws[k * 48 + c], s);
    y1[t] = s > 0.f ? s : 0.f;
}

// ---- g2 = dinv * (y1 @ W2), 48 -> 32 ----------------------------------------
__global__ void k_gemm2(const float* __restrict__ y1, const float* __restrict__ W2,
                        const float* __restrict__ dinv, float* __restrict__ g2, int n) {
    __shared__ float Ws[48 * 32];
    for (int i = threadIdx.x; i < 48 * 32; i += blockDim.x) Ws[i] = W2[i];
    __syncthreads();
    int t = blockIdx.x * blockDim.x + threadIdx.x;
    int v = t / 32, j = t % 32;
    if (v >= n) return;
    const float* yr = y1 + (long long)v * 48;
    float s = 0.f;
#pragma unroll
    for (int c = 0; c < 48; ++c) s = fmaf(yr[c], Ws[c * 32 + j], s);
    g2[t] = s * dinv[v];
}

// ---- fc: out = y2 @ Wfc + bfc ----------------------------------------------
__global__ void k_fc(const float* __restrict__ y2, const float* __restrict__ Wfc,
                     const float* __restrict__ bfc, float* __restrict__ out, int n) {
    __shared__ float Ws[32 * 16];
    __shared__ float bs[16];
    for (int i = threadIdx.x; i < 32 * 16; i += blockDim.x) Ws[i] = Wfc[i];
    if (threadIdx.x < 16) bs[threadIdx.x] = bfc[threadIdx.x];
    __syncthreads();
    int t = blockIdx.x * blockDim.x + threadIdx.x;
    int v = t / 16, o = t % 16;
    if (v >= n) return;
    const float* yr = y2 + (long long)v * 32;
    float s = bs[o];
#pragma unroll
    for (int j = 0; j < 32; ++j) s = fmaf(yr[j], Ws[j * 16 + o], s);
    out[t] = s;
}

static inline int nblk(long long threads) { return (int)((threads + TPB - 1) / TPB); }

extern "C" void kernel_launch(void* const* d_in, const int* in_sizes, int n_in,
                              void* d_out, int out_size, void* d_ws, size_t ws_size,
                              hipStream_t stream) {
    const float* x   = (const float*)d_in[0];
    const int*  eidx = (const int*)d_in[1];
    const float* W1  = (const float*)d_in[2];
    const float* b1  = (const float*)d_in[3];
    const float* W2  = (const float*)d_in[4];
    const float* b2  = (const float*)d_in[5];
    const float* Wfc = (const float*)d_in[6];
    const float* bfc = (const float*)d_in[7];
    float* out = (float*)d_out;

    const int N = in_sizes[0] / 16;
    const int E = in_sizes[1] / 2;
    const int* src = eidx;
    const int* dst = eidx + E;
    const int NB = (N + G_SZ - 1) >> G_BITS;     // buckets (<= 512)

    // workspace layout
    float* fws  = (float*)d_ws;
    float* dinv = fws;                    // [N]
    float* xs   = dinv + N;               // [16N]  dinv*x
    float* agg1 = xs + 16LL * N;          // [16N]
    float* y1   = agg1 + 16LL * N;        // [48N]
    float* g2   = y1 + 48LL * N;          // [32N]
    float* y2   = g2 + 32LL * N;          // [32N]
    int* row_start   = (int*)(y2 + 32LL * N);            // [N+1]
    int* csr_src     = row_start + N + 1;                // [E]
    unsigned* pairs  = (unsigned*)(csr_src + E);         // [NB*B_CAP]
    int* bucket_fill = (int*)(pairs + (long long)NB * B_CAP); // [NB]
    int* bucket_base = bucket_fill + NB;                 // [NB+1]
    int* ov_cnt      = bucket_base + NB + 1;             // [1]
    uintptr_t pov = ((uintptr_t)(ov_cnt + 1) + 7) & ~(uintptr_t)7;
    int2* ov_pairs   = (int2*)pov;                       // [OV_CAP]

    // ---- CSR build (bucketed two-phase counting sort, hierarchical scan) ----
    k_zerofill<<<1, 512, 0, stream>>>(bucket_fill, ov_cnt, NB);
    kA_bin<<<(E + KA_TPB * KA_EPT - 1) / (KA_TPB * KA_EPT), KA_TPB, 0, stream>>>(
        src, dst, bucket_fill, pairs, ov_cnt, ov_pairs, E, NB);
    k_bscan<<<1, 512, 0, stream>>>(bucket_fill, ov_cnt, ov_pairs, bucket_base, row_start, NB, N);
    kD_finish<<<NB, TPB, 0, stream>>>(pairs, bucket_fill, bucket_base, ov_cnt, ov_pairs,
                                      row_start, dinv, csr_src, N);

    // ---- layer 1: aggregate-first (16ch), then transform ----
    k_prescale<<<nblk(4LL * N), TPB, 0, stream>>>(x, dinv, xs, N);
    k_gather<16, false><<<nblk(4LL * N), TPB, 0, stream>>>(xs, row_start, csr_src, dinv, nullptr, agg1, N);
    k_lin1<<<nblk(48LL * N), TPB, 0, stream>>>(agg1, W1, b1, y1, N);

    // ---- layer 2: transform-first (32ch) ----
    k_gemm2<<<nblk(32LL * N), TPB, 0, stream>>>(y1, W2, dinv, g2, N);
    k_gather<32, true><<<nblk(8LL * N), TPB, 0, stream>>>(g2, row_start, csr_src, dinv, b2, y2, N);

    // ---- fc ----
    k_fc<<<nblk(16LL * N), TPB, 0, stream>>>(y2, Wfc, bfc, out, N);
}

// Round 12
// 294.940 us; speedup vs baseline: 12.0883x; 1.1127x over previous
//
#include <hip/hip_runtime.h>
#include <hip/hip_fp16.h>

#define TPB 256
#define G_BITS 8
#define G_SZ 256            // nodes per bucket (pow2)
#define B_CAP 10240         // pair capacity per bucket (mean ~8184, +23 sigma)
#define KA_TPB 512
#define KA_EPT 16           // edges per thread in kA
#define OV_CAP 8192

// ---- zero bucket_fill + ov_cnt ---------------------------------------------
__global__ void k_zerofill(int* __restrict__ bucket_fill, int* __restrict__ ov_cnt, int NB) {
    int i = threadIdx.x;
    for (; i < NB; i += blockDim.x) bucket_fill[i] = 0;
    if (threadIdx.x == 0) *ov_cnt = 0;
}

// ---- pass A: bin edges into per-bucket regions as packed u32 ---------------
// pack = (local_dst << 20) | src   (src < 2^20)
__global__ void kA_bin(const int* __restrict__ src, const int* __restrict__ dst,
                       int* __restrict__ bucket_fill, unsigned* __restrict__ pairs,
                       int* __restrict__ ov_cnt, int2* __restrict__ ov_pairs,
                       int E, int NB) {
    __shared__ int hist[512];
    __shared__ int cur[512];
    const int base = blockIdx.x * (KA_TPB * KA_EPT);
    for (int i = threadIdx.x; i < NB; i += KA_TPB) hist[i] = 0;
    __syncthreads();
    int s[KA_EPT], d[KA_EPT];
#pragma unroll
    for (int k = 0; k < KA_EPT; ++k) {
        int e = base + (int)threadIdx.x + k * KA_TPB;
        if (e < E) { s[k] = src[e]; d[k] = dst[e]; }
        else       { s[k] = -1;     d[k] = 0;      }
    }
#pragma unroll
    for (int k = 0; k < KA_EPT; ++k)
        if (s[k] >= 0) atomicAdd(&hist[d[k] >> G_BITS], 1);
    __syncthreads();
    for (int b = threadIdx.x; b < NB; b += KA_TPB) {
        int h = hist[b];
        int start = h ? atomicAdd(&bucket_fill[b], h) : 0;
        cur[b] = b * B_CAP + start;
    }
    __syncthreads();
#pragma unroll
    for (int k = 0; k < KA_EPT; ++k) {
        if (s[k] < 0) continue;
        int b = d[k] >> G_BITS;
        int slot = atomicAdd(&cur[b], 1);
        if (slot < (b + 1) * B_CAP) {
            pairs[slot] = ((unsigned)(d[k] & (G_SZ - 1)) << 20) | (unsigned)s[k];
        } else {                                  // ~never: defensive overflow
            int o = atomicAdd(ov_cnt, 1);
            if (o < OV_CAP) ov_pairs[o] = make_int2(s[k], d[k]);
        }
    }
}

// ---- bucket-level scan: totals (placed + stored ov) -> bucket_base ---------
__global__ void k_bscan(const int* __restrict__ bucket_fill,
                        const int* __restrict__ ov_cnt, const int2* __restrict__ ov_pairs,
                        int* __restrict__ bucket_base, int* __restrict__ row_start,
                        int NB, int N) {
    __shared__ int tot[512];
    __shared__ int wsum[8];
    const int i = threadIdx.x;
    int f = 0;
    if (i < NB) { f = bucket_fill[i]; if (f > B_CAP) f = B_CAP; }
    tot[i] = f;
    __syncthreads();
    int nov = *ov_cnt; if (nov > OV_CAP) nov = OV_CAP;
    for (int j = i; j < nov; j += 512)
        atomicAdd(&tot[ov_pairs[j].y >> G_BITS], 1);
    __syncthreads();
    int v = tot[i];
    const int lane = i & 63, wid = i >> 6;
    int incl = v;
#pragma unroll
    for (int off = 1; off < 64; off <<= 1) {
        int t = __shfl_up(incl, off, 64);
        if (lane >= off) incl += t;
    }
    if (lane == 63) wsum[wid] = incl;
    __syncthreads();
    int woff = 0;
    for (int w = 0; w < wid; ++w) woff += wsum[w];
    int ex = woff + incl - v;                 // exclusive prefix
    if (i < NB) bucket_base[i] = ex;
    if (i == NB - 1) { bucket_base[NB] = ex + v; row_start[N] = ex + v; }
}

// ---- per-bucket: hist -> local scan -> row_start/dinv -> place csr ---------
__global__ void kD_finish(const unsigned* __restrict__ pairs, const int* __restrict__ bucket_fill,
                          const int* __restrict__ bucket_base,
                          const int* __restrict__ ov_cnt, const int2* __restrict__ ov_pairs,
                          int* __restrict__ row_start, float* __restrict__ dinv,
                          int* __restrict__ csr_src, int N) {
    __shared__ int hist[G_SZ];
    __shared__ int cur[G_SZ];
    __shared__ int wsum[G_SZ / 64];
    const int b = blockIdx.x;
    const int lo = b << G_BITS;
    hist[threadIdx.x] = 0;                    // TPB == G_SZ
    __syncthreads();
    int fill = bucket_fill[b]; if (fill > B_CAP) fill = B_CAP;
    const unsigned* p = pairs + (long long)b * B_CAP;
    for (int j = threadIdx.x; j < fill; j += TPB)
        atomicAdd(&hist[p[j] >> 20], 1);
    int nov = *ov_cnt; if (nov > OV_CAP) nov = OV_CAP;
    for (int j = threadIdx.x; j < nov; j += TPB) {
        int d = ov_pairs[j].y;
        if ((d >> G_BITS) == b) atomicAdd(&hist[d & (G_SZ - 1)], 1);
    }
    __syncthreads();
    const int i = threadIdx.x;
    int v = hist[i];
    const int lane = i & 63, wid = i >> 6;
    int incl = v;
#pragma unroll
    for (int off = 1; off < 64; off <<= 1) {
        int t = __shfl_up(incl, off, 64);
        if (lane >= off) incl += t;
    }
    if (lane == 63) wsum[wid] = incl;
    __syncthreads();
    int woff = 0;
    for (int w = 0; w < wid; ++w) woff += wsum[w];
    int ex = bucket_base[b] + woff + incl - v;   // global exclusive prefix
    if (lo + i < N) {
        row_start[lo + i] = ex;
        dinv[lo + i] = rsqrtf((float)(v + 1));   // +1 self-loop
    }
    cur[i] = ex;
    __syncthreads();
    for (int j = threadIdx.x; j < fill; j += TPB) {
        unsigned pv = p[j];
        int pos = atomicAdd(&cur[pv >> 20], 1);
        csr_src[pos] = (int)(pv & 0xFFFFFu);
    }
    for (int j = threadIdx.x; j < nov; j += TPB) {
        int d = ov_pairs[j].y;
        if ((d >> G_BITS) == b) {
            int pos = atomicAdd(&cur[d & (G_SZ - 1)], 1);
            csr_src[pos] = ov_pairs[j].x;
        }
    }
}

// ---- xs_h = fp16(dinv[v] * x[v])  (16ch, 32B rows) --------------------------
__global__ void k_prescale_h(const float* __restrict__ x, const float* __restrict__ dinv,
                             __half* __restrict__ xs, int n) {
    int t = blockIdx.x * blockDim.x + threadIdx.x;   // 2 threads per node
    int v = t >> 1, h = t & 1;
    if (v >= n) return;
    float di = dinv[v];
    const float4* x4 = reinterpret_cast<const float4*>(x) + (long long)v * 4 + h * 2;
    float4 a = x4[0], b = x4[1];
    __half2 p0 = __floats2half2_rn(a.x * di, a.y * di);
    __half2 p1 = __floats2half2_rn(a.z * di, a.w * di);
    __half2 p2 = __floats2half2_rn(b.x * di, b.y * di);
    __half2 p3 = __floats2half2_rn(b.z * di, b.w * di);
    uint4 u;
    u.x = *reinterpret_cast<unsigned*>(&p0);
    u.y = *reinterpret_cast<unsigned*>(&p1);
    u.z = *reinterpret_cast<unsigned*>(&p2);
    u.w = *reinterpret_cast<unsigned*>(&p3);
    reinterpret_cast<uint4*>(xs)[(long long)v * 2 + h] = u;
}

__device__ __forceinline__ void acc8(float* acc, const uint4& u) {
    const __half2* h = reinterpret_cast<const __half2*>(&u);
#pragma unroll
    for (int i = 0; i < 4; ++i) {
        float2 f = __half22float2(h[i]);
        acc[2 * i]     += f.x;
        acc[2 * i + 1] += f.y;
    }
}

// ---- gather layer 1: agg1 = dinv*(xs[v] + sum xs[s]), 16ch fp16 in ---------
__global__ void k_gather1h(const __half* __restrict__ g, const int* __restrict__ row_start,
                           const int* __restrict__ csr_src, const float* __restrict__ dinv,
                           float* __restrict__ agg1, int n) {
    int t = blockIdx.x * blockDim.x + threadIdx.x;   // 2 lanes per node, 8ch each
    int v = t >> 1, q = t & 1;
    if (v >= n) return;
    const uint4* gq = reinterpret_cast<const uint4*>(g);   // 16B = 8 halves
    float acc[8];
    {
        uint4 u = gq[(long long)v * 2 + q];
        const __half2* h = reinterpret_cast<const __half2*>(&u);
#pragma unroll
        for (int i = 0; i < 4; ++i) {
            float2 f = __half22float2(h[i]);
            acc[2 * i] = f.x; acc[2 * i + 1] = f.y;
        }
    }
    int beg = row_start[v], end = row_start[v + 1];
    int j = beg;
    for (; j + 2 <= end; j += 2) {
        int s0 = csr_src[j], s1 = csr_src[j + 1];
        uint4 u0 = gq[(long long)s0 * 2 + q];
        uint4 u1 = gq[(long long)s1 * 2 + q];
        acc8(acc, u0);
        acc8(acc, u1);
    }
    if (j < end) {
        uint4 u = gq[(long long)csr_src[j] * 2 + q];
        acc8(acc, u);
    }
    float di = dinv[v];
    float4* outp = reinterpret_cast<float4*>(agg1) + (long long)v * 4 + q * 2;
    outp[0] = make_float4(acc[0] * di, acc[1] * di, acc[2] * di, acc[3] * di);
    outp[1] = make_float4(acc[4] * di, acc[5] * di, acc[6] * di, acc[7] * di);
}

// ---- y1 = relu(agg1 @ W1 + b1), 16 -> 48 ------------------------------------
__global__ void k_lin1(const float* __restrict__ agg1, const float* __restrict__ W1,
                       const float* __restrict__ b1, float* __restrict__ y1, int n) {
    __shared__ float Ws[16 * 48];
    __shared__ float bs[48];
    for (int i = threadIdx.x; i < 16 * 48; i += blockDim.x) Ws[i] = W1[i];
    if (threadIdx.x < 48) bs[threadIdx.x] = b1[threadIdx.x];
    __syncthreads();
    int t = blockIdx.x * blockDim.x + threadIdx.x;
    int v = t / 48, c = t % 48;
    if (v >= n) return;
    const float* ar = agg1 + (long long)v * 16;
    float s = bs[c];
#pragma unroll
    for (int k = 0; k < 16; ++k) s = fmaf(ar[k], Ws[k * 48 + c], s);
    y1[t] = s > 0.f ? s : 0.f;
}

// ---- g2h = fp16(dinv * (y1 @ W2)), 48 -> 32 ---------------------------------
__global__ void k_gemm2h(const float* __restrict__ y1, const float* __restrict__ W2,
                         const float* __restrict__ dinv, __half* __restrict__ g2h, int n) {
    __shared__ float Ws[48 * 32];
    for (int i = threadIdx.x; i < 48 * 32; i += blockDim.x) Ws[i] = W2[i];
    __syncthreads();
    int t = blockIdx.x * blockDim.x + threadIdx.x;
    int v = t / 32, j = t % 32;
    if (v >= n) return;
    const float* yr = y1 + (long long)v * 48;
    float s = 0.f;
#pragma unroll
    for (int c = 0; c < 48; ++c) s = fmaf(yr[c], Ws[c * 32 + j], s);
    g2h[t] = __float2half_rn(s * dinv[v]);
}

// ---- gather layer 2: y2 = relu(dinv*(g2[v] + sum g2[s]) + b2), 32ch fp16 in -
__global__ void k_gather2h(const __half* __restrict__ g, const int* __restrict__ row_start,
                           const int* __restrict__ csr_src, const float* __restrict__ dinv,
                           const float* __restrict__ bias, float* __restrict__ y2, int n) {
    int t = blockIdx.x * blockDim.x + threadIdx.x;   // 4 lanes per node, 8ch each
    int v = t >> 2, q = t & 3;
    if (v >= n) return;
    const uint4* gq = reinterpret_cast<const uint4*>(g);   // 16B = 8 halves
    float acc[8];
    {
        uint4 u = gq[(long long)v * 4 + q];
        const __half2* h = reinterpret_cast<const __half2*>(&u);
#pragma unroll
        for (int i = 0; i < 4; ++i) {
            float2 f = __half22float2(h[i]);
            acc[2 * i] = f.x; acc[2 * i + 1] = f.y;
        }
    }
    int beg = row_start[v], end = row_start[v + 1];
    int j = beg;
    for (; j + 2 <= end; j += 2) {
        int s0 = csr_src[j], s1 = csr_src[j + 1];
        uint4 u0 = gq[(long long)s0 * 4 + q];
        uint4 u1 = gq[(long long)s1 * 4 + q];
        acc8(acc, u0);
        acc8(acc, u1);
    }
    if (j < end) {
        uint4 u = gq[(long long)csr_src[j] * 4 + q];
        acc8(acc, u);
    }
    float di = dinv[v];
    const float4* b4 = reinterpret_cast<const float4*>(bias) + q * 2;
    float4 ba = b4[0], bb = b4[1];
    float4 o0, o1;
    o0.x = fmaxf(fmaf(di, acc[0], ba.x), 0.f);
    o0.y = fmaxf(fmaf(di, acc[1], ba.y), 0.f);
    o0.z = fmaxf(fmaf(di, acc[2], ba.z), 0.f);
    o0.w = fmaxf(fmaf(di, acc[3], ba.w), 0.f);
    o1.x = fmaxf(fmaf(di, acc[4], bb.x), 0.f);
    o1.y = fmaxf(fmaf(di, acc[5], bb.y), 0.f);
    o1.z = fmaxf(fmaf(di, acc[6], bb.z), 0.f);
    o1.w = fmaxf(fmaf(di, acc[7], bb.w), 0.f);
    float4* outp = reinterpret_cast<float4*>(y2) + (long long)v * 8 + q * 2;
    outp[0] = o0; outp[1] = o1;
}

// ---- fc: out = y2 @ Wfc + bfc ----------------------------------------------
__global__ void k_fc(const float* __restrict__ y2, const float* __restrict__ Wfc,
                     const float* __restrict__ bfc, float* __restrict__ out, int n) {
    __shared__ float Ws[32 * 16];
    __shared__ float bs[16];
    for (int i = threadIdx.x; i < 32 * 16; i += blockDim.x) Ws[i] = Wfc[i];
    if (threadIdx.x < 16) bs[threadIdx.x] = bfc[threadIdx.x];
    __syncthreads();
    int t = blockIdx.x * blockDim.x + threadIdx.x;
    int v = t / 16, o = t % 16;
    if (v >= n) return;
    const float* yr = y2 + (long long)v * 32;
    float s = bs[o];
#pragma unroll
    for (int j = 0; j < 32; ++j) s = fmaf(yr[j], Ws[j * 16 + o], s);
    out[t] = s;
}

static inline int nblk(long long threads) { return (int)((threads + TPB - 1) / TPB); }

extern "C" void kernel_launch(void* const* d_in, const int* in_sizes, int n_in,
                              void* d_out, int out_size, void* d_ws, size_t ws_size,
                              hipStream_t stream) {
    const float* x   = (const float*)d_in[0];
    const int*  eidx = (const int*)d_in[1];
    const float* W1  = (const float*)d_in[2];
    const float* b1  = (const float*)d_in[3];
    const float* W2  = (const float*)d_in[4];
    const float* b2  = (const float*)d_in[5];
    const float* Wfc = (const float*)d_in[6];
    const float* bfc = (const float*)d_in[7];
    float* out = (float*)d_out;

    const int N = in_sizes[0] / 16;
    const int E = in_sizes[1] / 2;
    const int* src = eidx;
    const int* dst = eidx + E;
    const int NB = (N + G_SZ - 1) >> G_BITS;     // buckets (<= 512)

    // workspace layout (N % 4 == 0 keeps 16B alignment everywhere)
    float* fws  = (float*)d_ws;
    float* dinv = fws;                            // [N]    f32
    __half* xs_h = (__half*)(dinv + N);           // [16N]  half (= 8N f32)
    float* agg1 = (float*)(xs_h + 16LL * N);      // [16N]  f32
    float* y1   = agg1 + 16LL * N;                // [48N]  f32
    __half* g2h = (__half*)(y1 + 48LL * N);       // [32N]  half (= 16N f32)
    float* y2   = (float*)(g2h + 32LL * N);       // [32N]  f32
    int* row_start   = (int*)(y2 + 32LL * N);            // [N+1]
    int* csr_src     = row_start + N + 1;                // [E]
    unsigned* pairs  = (unsigned*)(csr_src + E);         // [NB*B_CAP]
    int* bucket_fill = (int*)(pairs + (long long)NB * B_CAP); // [NB]
    int* bucket_base = bucket_fill + NB;                 // [NB+1]
    int* ov_cnt      = bucket_base + NB + 1;             // [1]
    uintptr_t pov = ((uintptr_t)(ov_cnt + 1) + 7) & ~(uintptr_t)7;
    int2* ov_pairs   = (int2*)pov;                       // [OV_CAP]

    // ---- CSR build (bucketed two-phase counting sort, hierarchical scan) ----
    k_zerofill<<<1, 512, 0, stream>>>(bucket_fill, ov_cnt, NB);
    kA_bin<<<(E + KA_TPB * KA_EPT - 1) / (KA_TPB * KA_EPT), KA_TPB, 0, stream>>>(
        src, dst, bucket_fill, pairs, ov_cnt, ov_pairs, E, NB);
    k_bscan<<<1, 512, 0, stream>>>(bucket_fill, ov_cnt, ov_pairs, bucket_base, row_start, NB, N);
    kD_finish<<<NB, TPB, 0, stream>>>(pairs, bucket_fill, bucket_base, ov_cnt, ov_pairs,
                                      row_start, dinv, csr_src, N);

    // ---- layer 1: aggregate-first (16ch fp16 messages), then transform ----
    k_prescale_h<<<nblk(2LL * N), TPB, 0, stream>>>(x, dinv, xs_h, N);
    k_gather1h<<<nblk(2LL * N), TPB, 0, stream>>>(xs_h, row_start, csr_src, dinv, agg1, N);
    k_lin1<<<nblk(48LL * N), TPB, 0, stream>>>(agg1, W1, b1, y1, N);

    // ---- layer 2: transform-first (32ch fp16 messages) ----
    k_gemm2h<<<nblk(32LL * N), TPB, 0, stream>>>(y1, W2, dinv, g2h, N);
    k_gather2h<<<nblk(4LL * N), TPB, 0, stream>>>(g2h, row_start, csr_src, dinv, b2, y2, N);

    // ---- fc ----
    k_fc<<<nblk(16LL * N), TPB, 0, stream>>>(y2, Wfc, bfc, out, N);
}